// Round 1
// baseline (315.434 us; speedup 1.0000x reference)
//
#include <hip/hip_runtime.h>

#define NROWS 4096
#define DCOLS 8192
#define DIM   256
#define NHALF 4096

typedef __attribute__((ext_vector_type(8))) short bf16x8;
typedef __attribute__((ext_vector_type(4))) float f32x4;
typedef __attribute__((ext_vector_type(4))) unsigned short ushort4v;
typedef __attribute__((ext_vector_type(4))) _Float16 half4;
typedef __attribute__((ext_vector_type(8))) _Float16 half8;

static __device__ __forceinline__ unsigned short f2bf(float f) {
  union { float f; unsigned int i; } v; v.f = f;
  unsigned int x = v.i;
  return (unsigned short)((x + 0x7fffu + ((x >> 16) & 1u)) >> 16);
}

static __device__ __forceinline__ void gload_lds16(const void* g, void* l) {
  __builtin_amdgcn_global_load_lds(
      (const __attribute__((address_space(1))) void*)g,
      (__attribute__((address_space(3))) void*)l, 16, 0, 0);
}

// ---------------- prep: bf16 convert + row norms ----------------
__global__ __launch_bounds__(256) void k_prep(
    const float* __restrict__ x, const float* __restrict__ ypos,
    const float* __restrict__ yneg, unsigned short* __restrict__ xb,
    unsigned short* __restrict__ yb, float* __restrict__ xx, float* __restrict__ yy) {
  int b = blockIdx.x, t = threadIdx.x;
  const float* src; unsigned short* dst; float* nrm;
  if (b < 4096)      { src = x + (size_t)b * DIM;             dst = xb + (size_t)b * DIM;            nrm = xx + b; }
  else if (b < 8192) { int r = b - 4096; src = yneg + (size_t)r * DIM; dst = yb + (size_t)r * DIM;   nrm = yy + r; }
  else               { int r = b - 8192; src = ypos + (size_t)r * DIM; dst = yb + (size_t)(NHALF + r) * DIM; nrm = yy + NHALF + r; }
  float v = src[t];
  dst[t] = f2bf(v);
  float s = v * v;
  #pragma unroll
  for (int o = 32; o > 0; o >>= 1) s += __shfl_xor(s, o);
  __shared__ float red[4];
  if ((t & 63) == 0) red[t >> 6] = s;
  __syncthreads();
  if (t == 0) nrm[0] = red[0] + red[1] + red[2] + red[3];
}

// ---------------- transpose yb (8192x256) -> ybt (256x8192) ----------------
__global__ __launch_bounds__(256) void k_transpose(
    const unsigned short* __restrict__ yb, unsigned short* __restrict__ ybt) {
  __shared__ unsigned short tile[64][68];
  int r0 = blockIdx.x * 64;   // 128 blocks over 8192 rows
  int c0 = blockIdx.y * 64;   // 4 blocks over 256 cols
  int tx = threadIdx.x & 63, ty = threadIdx.x >> 6;
  #pragma unroll
  for (int it = 0; it < 16; ++it) {
    int r = it * 4 + ty;
    tile[r][tx] = yb[(size_t)(r0 + r) * DIM + c0 + tx];
  }
  __syncthreads();
  #pragma unroll
  for (int it = 0; it < 16; ++it) {
    int c = it * 4 + ty;
    ybt[(size_t)(c0 + c) * DCOLS + r0 + tx] = tile[tx][c];
  }
}

// ---------------- dist GEMM: dist[i][j] fp16, + mean(dist_pos) ----------------
__global__ __launch_bounds__(256) void k_dist(
    const unsigned short* __restrict__ xb, const unsigned short* __restrict__ yb,
    const float* __restrict__ xx, const float* __restrict__ yy,
    unsigned short* __restrict__ distbuf, double* __restrict__ meanacc) {
  __shared__ unsigned short As[128 * 64];
  __shared__ unsigned short Bs[128 * 64];
  __shared__ float red[4];
  const int bj = blockIdx.x * 128;
  const int bi = blockIdx.y * 128;
  const int tid = threadIdx.x;
  const int lane = tid & 63, wid = tid >> 6;
  const int wr = wid >> 1, wc = wid & 1;
  f32x4 acc[4][4];
  #pragma unroll
  for (int m = 0; m < 4; ++m)
    #pragma unroll
    for (int n = 0; n < 4; ++n) acc[m][n] = (f32x4){0.f, 0.f, 0.f, 0.f};

  for (int k0 = 0; k0 < DIM; k0 += 64) {
    __syncthreads();
    #pragma unroll
    for (int it = 0; it < 4; ++it) {
      int L = it * 256 + tid;
      int row = L >> 3;
      int cb = (L & 7) * 16;
      int cbs = cb ^ ((row & 7) << 4);   // XOR-swizzle (T2; source pre-swizzled)
      gload_lds16(xb + (size_t)(bi + row) * DIM + k0 + (cbs >> 1), (char*)As + L * 16);
      gload_lds16(yb + (size_t)(bj + row) * DIM + k0 + (cbs >> 1), (char*)Bs + L * 16);
    }
    __syncthreads();
    #pragma unroll
    for (int kk = 0; kk < 2; ++kk) {
      bf16x8 a[4], b[4];
      #pragma unroll
      for (int m = 0; m < 4; ++m) {
        int row = wr * 64 + m * 16 + (lane & 15);
        int cb = (kk * 64 + ((lane >> 4) * 16)) ^ ((row & 7) << 4);
        a[m] = *(const bf16x8*)((const char*)As + row * 128 + cb);
      }
      #pragma unroll
      for (int n = 0; n < 4; ++n) {
        int row = wc * 64 + n * 16 + (lane & 15);
        int cb = (kk * 64 + ((lane >> 4) * 16)) ^ ((row & 7) << 4);
        b[n] = *(const bf16x8*)((const char*)Bs + row * 128 + cb);
      }
      #pragma unroll
      for (int m = 0; m < 4; ++m)
        #pragma unroll
        for (int n = 0; n < 4; ++n)
          acc[m][n] = __builtin_amdgcn_mfma_f32_16x16x32_bf16(a[m], b[n], acc[m][n], 0, 0, 0);
    }
  }

  const bool pos = (bj >= NHALF);
  float xv[16], yv[4];
  #pragma unroll
  for (int m = 0; m < 4; ++m)
    #pragma unroll
    for (int r = 0; r < 4; ++r)
      xv[m * 4 + r] = xx[bi + wr * 64 + m * 16 + (lane >> 4) * 4 + r];
  #pragma unroll
  for (int n = 0; n < 4; ++n)
    yv[n] = yy[bj + wc * 64 + n * 16 + (lane & 15)];

  _Float16* dp = (_Float16*)distbuf;
  float lsum = 0.f;
  #pragma unroll
  for (int m = 0; m < 4; ++m) {
    #pragma unroll
    for (int n = 0; n < 4; ++n) {
      #pragma unroll
      for (int r = 0; r < 4; ++r) {
        int gi = bi + wr * 64 + m * 16 + (lane >> 4) * 4 + r;
        int gj = bj + wc * 64 + n * 16 + (lane & 15);
        float d2 = xv[m * 4 + r] + yv[n] - 2.f * acc[m][n][r];
        float d = sqrtf(fmaxf(d2, 0.f));
        dp[(size_t)gi * DCOLS + gj] = (_Float16)d;
        lsum += d;
      }
    }
  }
  if (pos) {
    #pragma unroll
    for (int o = 32; o > 0; o >>= 1) lsum += __shfl_xor(lsum, o);
    if (lane == 0) red[wid] = lsum;
    __syncthreads();
    if (tid == 0) atomicAdd(meanacc, (double)(red[0] + red[1] + red[2] + red[3]));
  }
}

// ---------------- col sums per T (partials over 128-row slabs) ----------------
__global__ __launch_bounds__(256) void k_colsum(
    const _Float16* __restrict__ dist, const double* __restrict__ meanacc,
    float* __restrict__ cs_part) {
  const int cb = blockIdx.x & 7, rb = blockIdx.x >> 3;
  const int t = threadIdx.x;
  const int c0 = cb * 1024 + t * 4;
  const float md = (float)(meanacc[0] * (1.0 / 16777216.0));
  const float ia0 = 1.f / (0.05f * md), ia1 = 1.f / (0.1f * md), ia2 = 1.f / (0.2f * md);
  const bool neg = (cb < 4);
  float a0[4] = {0,0,0,0}, a1[4] = {0,0,0,0}, a2[4] = {0,0,0,0};
  #pragma unroll 2
  for (int r = rb * 128; r < rb * 128 + 128; ++r) {
    half4 h = *(const half4*)(dist + (size_t)r * DCOLS + c0);
    #pragma unroll
    for (int u = 0; u < 4; ++u) {
      if (neg && (c0 + u == r)) continue;
      float d = (float)h[u];
      a0[u] += __expf(-d * ia0);
      a1[u] += __expf(-d * ia1);
      a2[u] += __expf(-d * ia2);
    }
  }
  *(f32x4*)(cs_part + (size_t)(rb * 3 + 0) * 8192 + c0) = (f32x4){a0[0], a0[1], a0[2], a0[3]};
  *(f32x4*)(cs_part + (size_t)(rb * 3 + 1) * 8192 + c0) = (f32x4){a1[0], a1[1], a1[2], a1[3]};
  *(f32x4*)(cs_part + (size_t)(rb * 3 + 2) * 8192 + c0) = (f32x4){a2[0], a2[1], a2[2], a2[3]};
}

__global__ __launch_bounds__(256) void k_colsum_reduce(
    const float* __restrict__ cs_part, float* __restrict__ cs) {
  int idx = blockIdx.x * 256 + threadIdx.x;  // < 3*8192
  float s = 0.f;
  #pragma unroll 8
  for (int rb = 0; rb < 32; ++rb) s += cs_part[(size_t)rb * 3 * 8192 + idx];
  cs[idx] = s;
}

// ---------------- row stats: rs (row sums), sn (sum A_neg), sp (sum A_pos) ----------------
__global__ __launch_bounds__(256) void k_rowstats(
    const _Float16* __restrict__ dist, const double* __restrict__ meanacc,
    const float* __restrict__ cs, float* __restrict__ rs,
    float* __restrict__ sn, float* __restrict__ sp) {
  const int lane = threadIdx.x & 63, w = threadIdx.x >> 6;
  const int i = blockIdx.x * 4 + w;   // 1024 blocks, 1 row per wave
  const float md = (float)(meanacc[0] * (1.0 / 16777216.0));
  const float ia0 = 1.f / (0.05f * md), ia1 = 1.f / (0.1f * md), ia2 = 1.f / (0.2f * md);
  const _Float16* row = dist + (size_t)i * DCOLS;

  float r0 = 0, r1 = 0, r2 = 0;
  #pragma unroll 4
  for (int it = 0; it < 16; ++it) {
    int j0 = it * 512 + lane * 8;
    half8 h = *(const half8*)(row + j0);
    #pragma unroll
    for (int u = 0; u < 8; ++u) {
      if (j0 + u == i) continue;
      float d = (float)h[u];
      r0 += __expf(-d * ia0); r1 += __expf(-d * ia1); r2 += __expf(-d * ia2);
    }
  }
  #pragma unroll
  for (int o = 32; o > 0; o >>= 1) {
    r0 += __shfl_xor(r0, o); r1 += __shfl_xor(r1, o); r2 += __shfl_xor(r2, o);
  }

  float n0 = 0, n1 = 0, n2 = 0, p0 = 0, p1 = 0, p2 = 0;
  #pragma unroll 2
  for (int it = 0; it < 16; ++it) {
    int j0 = it * 512 + lane * 8;
    half8 h = *(const half8*)(row + j0);
    f32x4 ca0 = *(const f32x4*)(cs + j0),          ca1 = *(const f32x4*)(cs + j0 + 4);
    f32x4 cb0 = *(const f32x4*)(cs + 8192 + j0),   cb1 = *(const f32x4*)(cs + 8192 + j0 + 4);
    f32x4 cc0 = *(const f32x4*)(cs + 16384 + j0),  cc1 = *(const f32x4*)(cs + 16384 + j0 + 4);
    float s0 = 0, s1 = 0, s2 = 0;
    #pragma unroll
    for (int u = 0; u < 8; ++u) {
      if (j0 + u == i) continue;
      float d = (float)h[u];
      float c0v = (u < 4) ? ca0[u] : ca1[u - 4];
      float c1v = (u < 4) ? cb0[u] : cb1[u - 4];
      float c2v = (u < 4) ? cc0[u] : cc1[u - 4];
      s0 += __expf(-d * ia0) * rsqrtf(fmaxf(r0 * c0v, 1e-12f));
      s1 += __expf(-d * ia1) * rsqrtf(fmaxf(r1 * c1v, 1e-12f));
      s2 += __expf(-d * ia2) * rsqrtf(fmaxf(r2 * c2v, 1e-12f));
    }
    if (it < 8) { n0 += s0; n1 += s1; n2 += s2; }
    else        { p0 += s0; p1 += s1; p2 += s2; }
  }
  #pragma unroll
  for (int o = 32; o > 0; o >>= 1) {
    n0 += __shfl_xor(n0, o); n1 += __shfl_xor(n1, o); n2 += __shfl_xor(n2, o);
    p0 += __shfl_xor(p0, o); p1 += __shfl_xor(p1, o); p2 += __shfl_xor(p2, o);
  }
  if (lane == 0) {
    rs[i] = r0; rs[4096 + i] = r1; rs[8192 + i] = r2;
    sn[i] = n0; sn[4096 + i] = n1; sn[8192 + i] = n2;
    sp[i] = p0; sp[4096 + i] = p1; sp[8192 + i] = p2;
  }
}

// ---------------- C matrix (bf16), in-place over dist buffer ----------------
__global__ __launch_bounds__(256) void k_cmat(
    unsigned short* __restrict__ buf, const double* __restrict__ meanacc,
    const float* __restrict__ cs, const float* __restrict__ rs,
    const float* __restrict__ sn, const float* __restrict__ sp) {
  const int cb = blockIdx.x & 7, rb = blockIdx.x >> 3;
  const int t = threadIdx.x;
  const int c0 = cb * 1024 + t * 4;
  const float md = (float)(meanacc[0] * (1.0 / 16777216.0));
  const float ia0 = 1.f / (0.05f * md), ia1 = 1.f / (0.1f * md), ia2 = 1.f / (0.2f * md);
  float cv0[4], cv1[4], cv2[4];
  {
    f32x4 c4;
    c4 = *(const f32x4*)(cs + c0);          cv0[0]=c4[0]; cv0[1]=c4[1]; cv0[2]=c4[2]; cv0[3]=c4[3];
    c4 = *(const f32x4*)(cs + 8192 + c0);   cv1[0]=c4[0]; cv1[1]=c4[1]; cv1[2]=c4[2]; cv1[3]=c4[3];
    c4 = *(const f32x4*)(cs + 16384 + c0);  cv2[0]=c4[0]; cv2[1]=c4[1]; cv2[2]=c4[2]; cv2[3]=c4[3];
  }
  const bool neg = (cb < 4);
  for (int r = rb * 128; r < rb * 128 + 128; ++r) {
    size_t base = (size_t)r * DCOLS + c0;
    half4 h = *(const half4*)((const _Float16*)buf + base);
    float rv0 = rs[r], rv1 = rs[4096 + r], rv2 = rs[8192 + r];
    float f0, f1, f2;
    if (neg) { f0 = -sp[r]; f1 = -sp[4096 + r]; f2 = -sp[8192 + r]; }
    else     { f0 =  sn[r]; f1 =  sn[4096 + r]; f2 =  sn[8192 + r]; }
    ushort4v outv;
    #pragma unroll
    for (int u = 0; u < 4; ++u) {
      float C = 0.f;
      if (!(neg && (c0 + u == r))) {
        float d = (float)h[u];
        C  = __expf(-d * ia0) * rsqrtf(fmaxf(rv0 * cv0[u], 1e-12f)) * f0;
        C += __expf(-d * ia1) * rsqrtf(fmaxf(rv1 * cv1[u], 1e-12f)) * f1;
        C += __expf(-d * ia2) * rsqrtf(fmaxf(rv2 * cv2[u], 1e-12f)) * f2;
      }
      outv[u] = f2bf(C);
    }
    *(ushort4v*)(buf + base) = outv;
  }
}

// ---------------- V GEMM: vpart[kc] = C[:, kc-chunk] @ Yb[kc-chunk, :] ----------------
__global__ __launch_bounds__(256) void k_vgemm(
    const unsigned short* __restrict__ cm, const unsigned short* __restrict__ ybt,
    float* __restrict__ vpart) {
  __shared__ unsigned short As[128 * 64];
  __shared__ unsigned short Bs[128 * 64];
  const int kc = blockIdx.x;   // 0..3
  const int cb = blockIdx.y;   // 0..1
  const int rb = blockIdx.z;   // 0..31
  const int tid = threadIdx.x;
  const int lane = tid & 63, wid = tid >> 6;
  const int wr = wid >> 1, wc = wid & 1;
  f32x4 acc[4][4];
  #pragma unroll
  for (int m = 0; m < 4; ++m)
    #pragma unroll
    for (int n = 0; n < 4; ++n) acc[m][n] = (f32x4){0.f, 0.f, 0.f, 0.f};

  for (int jt = 0; jt < 2048; jt += 64) {
    const int j0 = kc * 2048 + jt;
    __syncthreads();
    #pragma unroll
    for (int it = 0; it < 4; ++it) {
      int L = it * 256 + tid;
      int row = L >> 3;
      int cbyte = (L & 7) * 16;
      int cbs = cbyte ^ ((row & 7) << 4);
      gload_lds16(cm + (size_t)(rb * 128 + row) * DCOLS + j0 + (cbs >> 1), (char*)As + L * 16);
      gload_lds16(ybt + (size_t)(cb * 128 + row) * DCOLS + j0 + (cbs >> 1), (char*)Bs + L * 16);
    }
    __syncthreads();
    #pragma unroll
    for (int kk = 0; kk < 2; ++kk) {
      bf16x8 a[4], b[4];
      #pragma unroll
      for (int m = 0; m < 4; ++m) {
        int row = wr * 64 + m * 16 + (lane & 15);
        int cbyte = (kk * 64 + ((lane >> 4) * 16)) ^ ((row & 7) << 4);
        a[m] = *(const bf16x8*)((const char*)As + row * 128 + cbyte);
      }
      #pragma unroll
      for (int n = 0; n < 4; ++n) {
        int row = wc * 64 + n * 16 + (lane & 15);
        int cbyte = (kk * 64 + ((lane >> 4) * 16)) ^ ((row & 7) << 4);
        b[n] = *(const bf16x8*)((const char*)Bs + row * 128 + cbyte);
      }
      #pragma unroll
      for (int m = 0; m < 4; ++m)
        #pragma unroll
        for (int n = 0; n < 4; ++n)
          acc[m][n] = __builtin_amdgcn_mfma_f32_16x16x32_bf16(a[m], b[n], acc[m][n], 0, 0, 0);
    }
  }
  #pragma unroll
  for (int m = 0; m < 4; ++m)
    #pragma unroll
    for (int n = 0; n < 4; ++n)
      #pragma unroll
      for (int r = 0; r < 4; ++r) {
        int gi = rb * 128 + wr * 64 + m * 16 + (lane >> 4) * 4 + r;
        int gd = cb * 128 + wc * 64 + n * 16 + (lane & 15);
        vpart[(size_t)kc * 1048576 + (size_t)gi * 256 + gd] = acc[m][n][r];
      }
}

// ---------------- loss reduction ----------------
__global__ __launch_bounds__(256) void k_loss(
    const float* __restrict__ vpart, float* __restrict__ ploss) {
  int tid = blockIdx.x * 256 + threadIdx.x;
  float s = 0.f;
  for (int e = tid; e < 1048576; e += 65536) {
    float v = vpart[e] + vpart[e + 1048576] + vpart[e + 2097152] + vpart[e + 3145728];
    s += v * v;
  }
  #pragma unroll
  for (int o = 32; o > 0; o >>= 1) s += __shfl_xor(s, o);
  __shared__ float red[4];
  if ((threadIdx.x & 63) == 0) red[threadIdx.x >> 6] = s;
  __syncthreads();
  if (threadIdx.x == 0) ploss[blockIdx.x] = red[0] + red[1] + red[2] + red[3];
}

__global__ __launch_bounds__(256) void k_finish(
    const float* __restrict__ ploss, float* __restrict__ out) {
  float v = ploss[threadIdx.x];
  #pragma unroll
  for (int o = 32; o > 0; o >>= 1) v += __shfl_xor(v, o);
  __shared__ float red[4];
  if ((threadIdx.x & 63) == 0) red[threadIdx.x >> 6] = v;
  __syncthreads();
  if (threadIdx.x == 0)
    out[0] = (float)((double)(red[0] + red[1] + red[2] + red[3]) / 1048576.0);
}

extern "C" void kernel_launch(void* const* d_in, const int* in_sizes, int n_in,
                              void* d_out, int out_size, void* d_ws, size_t ws_size,
                              hipStream_t stream) {
  (void)in_sizes; (void)n_in; (void)out_size; (void)ws_size;
  const float* x    = (const float*)d_in[0];
  const float* ypos = (const float*)d_in[1];
  const float* yneg = (const float*)d_in[2];

  char* ws = (char*)d_ws;
  size_t o = 0;
  unsigned short* dist = (unsigned short*)(ws + o); o += (size_t)NROWS * DCOLS * 2;  // 64 MiB (dist fp16, later C bf16)
  unsigned short* xb   = (unsigned short*)(ws + o); o += (size_t)NROWS * DIM * 2;    // 2 MiB
  unsigned short* yb   = (unsigned short*)(ws + o); o += (size_t)DCOLS * DIM * 2;    // 4 MiB
  unsigned short* ybt  = (unsigned short*)(ws + o); o += (size_t)DCOLS * DIM * 2;    // 4 MiB
  float* xx      = (float*)(ws + o); o += NROWS * 4;
  float* yy      = (float*)(ws + o); o += DCOLS * 4;
  double* meanacc = (double*)(ws + o); o += 256;
  float* cs_part = (float*)(ws + o); o += (size_t)32 * 3 * DCOLS * 4;                // 3 MiB
  float* cs      = (float*)(ws + o); o += 3 * DCOLS * 4;
  float* rs      = (float*)(ws + o); o += 3 * NROWS * 4;
  float* sn      = (float*)(ws + o); o += 3 * NROWS * 4;
  float* sp      = (float*)(ws + o); o += 3 * NROWS * 4;
  float* vpart   = (float*)(ws + o); o += (size_t)4 * NROWS * DIM * 4;               // 16 MiB
  float* ploss   = (float*)(ws + o); o += 256 * 4;

  hipMemsetAsync(meanacc, 0, 8, stream);
  k_prep<<<12288, 256, 0, stream>>>(x, ypos, yneg, xb, yb, xx, yy);
  k_transpose<<<dim3(128, 4), 256, 0, stream>>>(yb, ybt);
  k_dist<<<dim3(64, 32), 256, 0, stream>>>(xb, yb, xx, yy, dist, meanacc);
  k_colsum<<<256, 256, 0, stream>>>((const _Float16*)dist, meanacc, cs_part);
  k_colsum_reduce<<<96, 256, 0, stream>>>(cs_part, cs);
  k_rowstats<<<1024, 256, 0, stream>>>((const _Float16*)dist, meanacc, cs, rs, sn, sp);
  k_cmat<<<256, 256, 0, stream>>>(dist, meanacc, cs, rs, sn, sp);
  k_vgemm<<<dim3(4, 2, 32), 256, 0, stream>>>(dist, ybt, vpart);
  k_loss<<<256, 256, 0, stream>>>(vpart, ploss);
  k_finish<<<1, 256, 0, stream>>>(ploss, (float*)d_out);
}

// Round 2
// 213.893 us; speedup vs baseline: 1.4747x; 1.4747x over previous
//
#include <hip/hip_runtime.h>

#define NROWS 4096
#define DCOLS 8192
#define DIM   256
#define NHALF 4096

typedef __attribute__((ext_vector_type(8))) short bf16x8;
typedef __attribute__((ext_vector_type(4))) float f32x4;
typedef __attribute__((ext_vector_type(4))) unsigned short ushort4v;
typedef __attribute__((ext_vector_type(8))) unsigned short ushort8v;
typedef __attribute__((ext_vector_type(4))) _Float16 half4;

static __device__ __forceinline__ unsigned short f2bf(float f) {
  union { float f; unsigned int i; } v; v.f = f;
  unsigned int x = v.i;
  return (unsigned short)((x + 0x7fffu + ((x >> 16) & 1u)) >> 16);
}

static __device__ __forceinline__ float h2f(unsigned short u) {
  _Float16 h; __builtin_memcpy(&h, &u, 2); return (float)h;
}

static __device__ __forceinline__ void gload_lds16(const void* g, void* l) {
  __builtin_amdgcn_global_load_lds(
      (const __attribute__((address_space(1))) void*)g,
      (__attribute__((address_space(3))) void*)l, 16, 0, 0);
}

#define WREDUCE(v) { v += __shfl_xor(v, 1); v += __shfl_xor(v, 2); v += __shfl_xor(v, 4); \
                     v += __shfl_xor(v, 8); v += __shfl_xor(v, 16); v += __shfl_xor(v, 32); }

// ---------------- prep: bf16 convert + row norms (wave per row, float4) ----------------
__global__ __launch_bounds__(256) void k_prep(
    const float* __restrict__ x, const float* __restrict__ ypos,
    const float* __restrict__ yneg, unsigned short* __restrict__ xb,
    unsigned short* __restrict__ yb, float* __restrict__ xx, float* __restrict__ yy) {
  const int lane = threadIdx.x & 63, w = threadIdx.x >> 6;
  const int b = blockIdx.x * 4 + w;   // 0..12287
  const float* src; unsigned short* dst; float* nrm;
  if (b < 4096)      { src = x + (size_t)b * DIM;             dst = xb + (size_t)b * DIM;            nrm = xx + b; }
  else if (b < 8192) { int r = b - 4096; src = yneg + (size_t)r * DIM; dst = yb + (size_t)r * DIM;   nrm = yy + r; }
  else               { int r = b - 8192; src = ypos + (size_t)r * DIM; dst = yb + (size_t)(NHALF + r) * DIM; nrm = yy + NHALF + r; }
  float4 v = *(const float4*)(src + lane * 4);
  ushort4v ov = { f2bf(v.x), f2bf(v.y), f2bf(v.z), f2bf(v.w) };
  *(ushort4v*)(dst + lane * 4) = ov;
  float s = v.x * v.x + v.y * v.y + v.z * v.z + v.w * v.w;
  WREDUCE(s);
  if (lane == 0) nrm[0] = s;
}

// ---------------- transpose yb (8192x256) -> ybt (256x8192) ----------------
__global__ __launch_bounds__(256) void k_transpose(
    const unsigned short* __restrict__ yb, unsigned short* __restrict__ ybt) {
  __shared__ unsigned short tile[64][68];
  int r0 = blockIdx.x * 64;
  int c0 = blockIdx.y * 64;
  int tx = threadIdx.x & 63, ty = threadIdx.x >> 6;
  #pragma unroll
  for (int it = 0; it < 16; ++it) {
    int r = it * 4 + ty;
    tile[r][tx] = yb[(size_t)(r0 + r) * DIM + c0 + tx];
  }
  __syncthreads();
  #pragma unroll
  for (int it = 0; it < 16; ++it) {
    int c = it * 4 + ty;
    ybt[(size_t)(c0 + c) * DCOLS + r0 + tx] = tile[tx][c];
  }
}

// ---------------- dist GEMM: dist[i][j] fp16, + mean(dist_pos) ----------------
__global__ __launch_bounds__(256) void k_dist(
    const unsigned short* __restrict__ xb, const unsigned short* __restrict__ yb,
    const float* __restrict__ xx, const float* __restrict__ yy,
    unsigned short* __restrict__ distbuf, double* __restrict__ meanacc) {
  __shared__ unsigned short As[128 * 64];
  __shared__ unsigned short Bs[128 * 64];
  __shared__ float red[4];
  const int bj = blockIdx.x * 128;
  const int bi = blockIdx.y * 128;
  const int tid = threadIdx.x;
  const int lane = tid & 63, wid = tid >> 6;
  const int wr = wid >> 1, wc = wid & 1;
  f32x4 acc[4][4];
  #pragma unroll
  for (int m = 0; m < 4; ++m)
    #pragma unroll
    for (int n = 0; n < 4; ++n) acc[m][n] = (f32x4){0.f, 0.f, 0.f, 0.f};

  for (int k0 = 0; k0 < DIM; k0 += 64) {
    __syncthreads();
    #pragma unroll
    for (int it = 0; it < 4; ++it) {
      int L = it * 256 + tid;
      int row = L >> 3;
      int cb = (L & 7) * 16;
      int cbs = cb ^ ((row & 7) << 4);
      gload_lds16(xb + (size_t)(bi + row) * DIM + k0 + (cbs >> 1), (char*)As + L * 16);
      gload_lds16(yb + (size_t)(bj + row) * DIM + k0 + (cbs >> 1), (char*)Bs + L * 16);
    }
    __syncthreads();
    #pragma unroll
    for (int kk = 0; kk < 2; ++kk) {
      bf16x8 a[4], b[4];
      #pragma unroll
      for (int m = 0; m < 4; ++m) {
        int row = wr * 64 + m * 16 + (lane & 15);
        int cb = (kk * 64 + ((lane >> 4) * 16)) ^ ((row & 7) << 4);
        a[m] = *(const bf16x8*)((const char*)As + row * 128 + cb);
      }
      #pragma unroll
      for (int n = 0; n < 4; ++n) {
        int row = wc * 64 + n * 16 + (lane & 15);
        int cb = (kk * 64 + ((lane >> 4) * 16)) ^ ((row & 7) << 4);
        b[n] = *(const bf16x8*)((const char*)Bs + row * 128 + cb);
      }
      #pragma unroll
      for (int m = 0; m < 4; ++m)
        #pragma unroll
        for (int n = 0; n < 4; ++n)
          acc[m][n] = __builtin_amdgcn_mfma_f32_16x16x32_bf16(a[m], b[n], acc[m][n], 0, 0, 0);
    }
  }

  const bool pos = (bj >= NHALF);
  float xv[16], yv[4];
  #pragma unroll
  for (int m = 0; m < 4; ++m)
    #pragma unroll
    for (int r = 0; r < 4; ++r)
      xv[m * 4 + r] = xx[bi + wr * 64 + m * 16 + (lane >> 4) * 4 + r];
  #pragma unroll
  for (int n = 0; n < 4; ++n)
    yv[n] = yy[bj + wc * 64 + n * 16 + (lane & 15)];

  _Float16* dp = (_Float16*)distbuf;
  float lsum = 0.f;
  #pragma unroll
  for (int m = 0; m < 4; ++m) {
    #pragma unroll
    for (int n = 0; n < 4; ++n) {
      #pragma unroll
      for (int r = 0; r < 4; ++r) {
        int gi = bi + wr * 64 + m * 16 + (lane >> 4) * 4 + r;
        int gj = bj + wc * 64 + n * 16 + (lane & 15);
        float d2 = xv[m * 4 + r] + yv[n] - 2.f * acc[m][n][r];
        float d = sqrtf(fmaxf(d2, 0.f));
        dp[(size_t)gi * DCOLS + gj] = (_Float16)d;
        lsum += d;
      }
    }
  }
  if (pos) {
    WREDUCE(lsum);
    if (lane == 0) red[wid] = lsum;
    __syncthreads();
    if (tid == 0) atomicAdd(meanacc, (double)(red[0] + red[1] + red[2] + red[3]));
  }
}

// ---------------- col sums per T (partials over 32-row slabs) ----------------
__global__ __launch_bounds__(256) void k_colsum(
    const _Float16* __restrict__ dist, const double* __restrict__ meanacc,
    float* __restrict__ cs_part) {
  const int cb = blockIdx.x & 7, rb = blockIdx.x >> 3;  // rb 0..127
  const int t = threadIdx.x;
  const int c0 = cb * 1024 + t * 4;
  const float md = (float)(meanacc[0] * (1.0 / 16777216.0));
  const float ia0 = 1.f / (0.05f * md), ia1 = 1.f / (0.1f * md), ia2 = 1.f / (0.2f * md);
  const bool neg = (cb < 4);
  float a0[4] = {0,0,0,0}, a1[4] = {0,0,0,0}, a2[4] = {0,0,0,0};
  const int rbeg = rb * 32;
  #pragma unroll 4
  for (int r = rbeg; r < rbeg + 32; ++r) {
    half4 h = *(const half4*)(dist + (size_t)r * DCOLS + c0);
    #pragma unroll
    for (int u = 0; u < 4; ++u) {
      if (neg && (c0 + u == r)) continue;
      float d = (float)h[u];
      a0[u] += __expf(-d * ia0);
      a1[u] += __expf(-d * ia1);
      a2[u] += __expf(-d * ia2);
    }
  }
  *(f32x4*)(cs_part + (size_t)(rb * 3 + 0) * 8192 + c0) = (f32x4){a0[0], a0[1], a0[2], a0[3]};
  *(f32x4*)(cs_part + (size_t)(rb * 3 + 1) * 8192 + c0) = (f32x4){a1[0], a1[1], a1[2], a1[3]};
  *(f32x4*)(cs_part + (size_t)(rb * 3 + 2) * 8192 + c0) = (f32x4){a2[0], a2[1], a2[2], a2[3]};
}

__global__ __launch_bounds__(256) void k_csred(
    const float* __restrict__ cs_part, float* __restrict__ cs) {
  const int idx = blockIdx.x * 256 + threadIdx.x;  // 0..24575
  const int s = blockIdx.y;                        // 0..3
  float acc = 0.f;
  #pragma unroll 8
  for (int rb = s * 32; rb < s * 32 + 32; ++rb)
    acc += cs_part[(size_t)rb * 24576 + idx];
  atomicAdd(cs + idx, acc);
}

// ---------------- fused row stats + C matrix (one wave per row) ----------------
__global__ __launch_bounds__(256) void k_rows(
    unsigned short* __restrict__ buf, const double* __restrict__ meanacc,
    const float* __restrict__ cs) {
  const int lane = threadIdx.x & 63, w = threadIdx.x >> 6;
  const int i = blockIdx.x * 4 + w;   // row 0..4095
  const float md = (float)(meanacc[0] * (1.0 / 16777216.0));
  const float ia0 = 1.f / (0.05f * md), ia1 = 1.f / (0.1f * md), ia2 = 1.f / (0.2f * md);
  unsigned short* rowp = buf + (size_t)i * DCOLS;

  // pass A: row sums per T
  float r0 = 0.f, r1 = 0.f, r2 = 0.f;
  #pragma unroll 4
  for (int it = 0; it < 16; ++it) {
    int j0 = it * 512 + lane * 8;
    ushort8v h = *(const ushort8v*)(rowp + j0);
    #pragma unroll
    for (int u = 0; u < 8; ++u) {
      if (j0 + u == i) continue;
      float d = h2f(h[u]);
      r0 += __expf(-d * ia0); r1 += __expf(-d * ia1); r2 += __expf(-d * ia2);
    }
  }
  WREDUCE(r0); WREDUCE(r1); WREDUCE(r2);

  // pass B: sn (sum over neg of A), sp (sum over pos of A)
  float n0 = 0, n1 = 0, n2 = 0, p0 = 0, p1 = 0, p2 = 0;
  #pragma unroll 2
  for (int it = 0; it < 16; ++it) {
    int j0 = it * 512 + lane * 8;
    ushort8v h = *(const ushort8v*)(rowp + j0);
    f32x4 ca0 = *(const f32x4*)(cs + j0),          ca1 = *(const f32x4*)(cs + j0 + 4);
    f32x4 cb0 = *(const f32x4*)(cs + 8192 + j0),   cb1 = *(const f32x4*)(cs + 8192 + j0 + 4);
    f32x4 cc0 = *(const f32x4*)(cs + 16384 + j0),  cc1 = *(const f32x4*)(cs + 16384 + j0 + 4);
    float s0 = 0, s1 = 0, s2 = 0;
    #pragma unroll
    for (int u = 0; u < 8; ++u) {
      if (j0 + u == i) continue;
      float d = h2f(h[u]);
      float c0v = (u < 4) ? ca0[u] : ca1[u - 4];
      float c1v = (u < 4) ? cb0[u] : cb1[u - 4];
      float c2v = (u < 4) ? cc0[u] : cc1[u - 4];
      s0 += __expf(-d * ia0) * rsqrtf(fmaxf(r0 * c0v, 1e-12f));
      s1 += __expf(-d * ia1) * rsqrtf(fmaxf(r1 * c1v, 1e-12f));
      s2 += __expf(-d * ia2) * rsqrtf(fmaxf(r2 * c2v, 1e-12f));
    }
    if (it < 8) { n0 += s0; n1 += s1; n2 += s2; }
    else        { p0 += s0; p1 += s1; p2 += s2; }
  }
  WREDUCE(n0); WREDUCE(n1); WREDUCE(n2);
  WREDUCE(p0); WREDUCE(p1); WREDUCE(p2);

  // pass C: write C (bf16) in place
  #pragma unroll 2
  for (int it = 0; it < 16; ++it) {
    int j0 = it * 512 + lane * 8;
    ushort8v h = *(const ushort8v*)(rowp + j0);
    f32x4 ca0 = *(const f32x4*)(cs + j0),          ca1 = *(const f32x4*)(cs + j0 + 4);
    f32x4 cb0 = *(const f32x4*)(cs + 8192 + j0),   cb1 = *(const f32x4*)(cs + 8192 + j0 + 4);
    f32x4 cc0 = *(const f32x4*)(cs + 16384 + j0),  cc1 = *(const f32x4*)(cs + 16384 + j0 + 4);
    float f0, f1, f2;
    if (it < 8) { f0 = -p0; f1 = -p1; f2 = -p2; }
    else        { f0 =  n0; f1 =  n1; f2 =  n2; }
    ushort8v outv;
    #pragma unroll
    for (int u = 0; u < 8; ++u) {
      float C = 0.f;
      if (!(j0 + u == i)) {
        float d = h2f(h[u]);
        float c0v = (u < 4) ? ca0[u] : ca1[u - 4];
        float c1v = (u < 4) ? cb0[u] : cb1[u - 4];
        float c2v = (u < 4) ? cc0[u] : cc1[u - 4];
        C  = __expf(-d * ia0) * rsqrtf(fmaxf(r0 * c0v, 1e-12f)) * f0;
        C += __expf(-d * ia1) * rsqrtf(fmaxf(r1 * c1v, 1e-12f)) * f1;
        C += __expf(-d * ia2) * rsqrtf(fmaxf(r2 * c2v, 1e-12f)) * f2;
      }
      outv[u] = f2bf(C);
    }
    *(ushort8v*)(rowp + j0) = outv;
  }
}

// ---------------- V GEMM: vpart[kc] = C[:, kc-chunk] @ Yb[kc-chunk, :] ----------------
__global__ __launch_bounds__(256) void k_vgemm(
    const unsigned short* __restrict__ cm, const unsigned short* __restrict__ ybt,
    float* __restrict__ vpart) {
  __shared__ unsigned short As[128 * 64];
  __shared__ unsigned short Bs[128 * 64];
  const int kc = blockIdx.x;   // 0..3
  const int cb = blockIdx.y;   // 0..1
  const int rb = blockIdx.z;   // 0..31
  const int tid = threadIdx.x;
  const int lane = tid & 63, wid = tid >> 6;
  const int wr = wid >> 1, wc = wid & 1;
  f32x4 acc[4][4];
  #pragma unroll
  for (int m = 0; m < 4; ++m)
    #pragma unroll
    for (int n = 0; n < 4; ++n) acc[m][n] = (f32x4){0.f, 0.f, 0.f, 0.f};

  for (int jt = 0; jt < 2048; jt += 64) {
    const int j0 = kc * 2048 + jt;
    __syncthreads();
    #pragma unroll
    for (int it = 0; it < 4; ++it) {
      int L = it * 256 + tid;
      int row = L >> 3;
      int cbyte = (L & 7) * 16;
      int cbs = cbyte ^ ((row & 7) << 4);
      gload_lds16(cm + (size_t)(rb * 128 + row) * DCOLS + j0 + (cbs >> 1), (char*)As + L * 16);
      gload_lds16(ybt + (size_t)(cb * 128 + row) * DCOLS + j0 + (cbs >> 1), (char*)Bs + L * 16);
    }
    __syncthreads();
    #pragma unroll
    for (int kk = 0; kk < 2; ++kk) {
      bf16x8 a[4], b[4];
      #pragma unroll
      for (int m = 0; m < 4; ++m) {
        int row = wr * 64 + m * 16 + (lane & 15);
        int cbyte = (kk * 64 + ((lane >> 4) * 16)) ^ ((row & 7) << 4);
        a[m] = *(const bf16x8*)((const char*)As + row * 128 + cbyte);
      }
      #pragma unroll
      for (int n = 0; n < 4; ++n) {
        int row = wc * 64 + n * 16 + (lane & 15);
        int cbyte = (kk * 64 + ((lane >> 4) * 16)) ^ ((row & 7) << 4);
        b[n] = *(const bf16x8*)((const char*)Bs + row * 128 + cbyte);
      }
      #pragma unroll
      for (int m = 0; m < 4; ++m)
        #pragma unroll
        for (int n = 0; n < 4; ++n)
          acc[m][n] = __builtin_amdgcn_mfma_f32_16x16x32_bf16(a[m], b[n], acc[m][n], 0, 0, 0);
    }
  }
  #pragma unroll
  for (int m = 0; m < 4; ++m)
    #pragma unroll
    for (int n = 0; n < 4; ++n)
      #pragma unroll
      for (int r = 0; r < 4; ++r) {
        int gi = rb * 128 + wr * 64 + m * 16 + (lane >> 4) * 4 + r;
        int gd = cb * 128 + wc * 64 + n * 16 + (lane & 15);
        vpart[(size_t)kc * 1048576 + (size_t)gi * 256 + gd] = acc[m][n][r];
      }
}

// ---------------- loss reduction ----------------
__global__ __launch_bounds__(256) void k_loss(
    const float* __restrict__ vpart, float* __restrict__ ploss) {
  int tid = blockIdx.x * 256 + threadIdx.x;   // grid 512
  float s = 0.f;
  for (int e = tid; e < 1048576; e += 131072) {
    float v = vpart[e] + vpart[e + 1048576] + vpart[e + 2097152] + vpart[e + 3145728];
    s += v * v;
  }
  WREDUCE(s);
  __shared__ float red[4];
  if ((threadIdx.x & 63) == 0) red[threadIdx.x >> 6] = s;
  __syncthreads();
  if (threadIdx.x == 0) ploss[blockIdx.x] = red[0] + red[1] + red[2] + red[3];
}

__global__ __launch_bounds__(256) void k_finish(
    const float* __restrict__ ploss, float* __restrict__ out) {
  float v = ploss[threadIdx.x] + ploss[threadIdx.x + 256];
  WREDUCE(v);
  __shared__ float red[4];
  if ((threadIdx.x & 63) == 0) red[threadIdx.x >> 6] = v;
  __syncthreads();
  if (threadIdx.x == 0)
    out[0] = (float)((double)(red[0] + red[1] + red[2] + red[3]) / 1048576.0);
}

extern "C" void kernel_launch(void* const* d_in, const int* in_sizes, int n_in,
                              void* d_out, int out_size, void* d_ws, size_t ws_size,
                              hipStream_t stream) {
  (void)in_sizes; (void)n_in; (void)out_size; (void)ws_size;
  const float* x    = (const float*)d_in[0];
  const float* ypos = (const float*)d_in[1];
  const float* yneg = (const float*)d_in[2];

  char* ws = (char*)d_ws;
  size_t o = 0;
  unsigned short* dist = (unsigned short*)(ws + o); o += (size_t)NROWS * DCOLS * 2;  // 64 MiB
  unsigned short* xb   = (unsigned short*)(ws + o); o += (size_t)NROWS * DIM * 2;    // 2 MiB
  unsigned short* yb   = (unsigned short*)(ws + o); o += (size_t)DCOLS * DIM * 2;    // 4 MiB
  unsigned short* ybt  = (unsigned short*)(ws + o); o += (size_t)DCOLS * DIM * 2;    // 4 MiB
  float* xx      = (float*)(ws + o); o += NROWS * 4;
  float* yy      = (float*)(ws + o); o += DCOLS * 4;
  double* meanacc = (double*)(ws + o); o += 256;
  float* cs      = (float*)(ws + o); o += 3 * DCOLS * 4;     // 96 KiB
  float* ploss   = (float*)(ws + o); o += 512 * 4;
  // union region: cs_part (12.6 MiB, dead after k_csred) aliased with vpart (16 MiB)
  float* cs_part = (float*)(ws + o);
  float* vpart   = (float*)(ws + o); o += (size_t)4 * NROWS * DIM * 4;               // 16 MiB

  hipMemsetAsync(meanacc, 0, 8, stream);
  hipMemsetAsync(cs, 0, 3 * DCOLS * 4, stream);
  k_prep<<<3072, 256, 0, stream>>>(x, ypos, yneg, xb, yb, xx, yy);
  k_transpose<<<dim3(128, 4), 256, 0, stream>>>(yb, ybt);
  k_dist<<<dim3(64, 32), 256, 0, stream>>>(xb, yb, xx, yy, dist, meanacc);
  k_colsum<<<1024, 256, 0, stream>>>((const _Float16*)dist, meanacc, cs_part);
  k_csred<<<dim3(96, 4), 256, 0, stream>>>(cs_part, cs);
  k_rows<<<1024, 256, 0, stream>>>(dist, meanacc, cs);
  k_vgemm<<<dim3(4, 2, 32), 256, 0, stream>>>(dist, ybt, vpart);
  k_loss<<<512, 256, 0, stream>>>(vpart, ploss);
  k_finish<<<1, 256, 0, stream>>>(ploss, (float*)d_out);
}

// Round 3
// 173.970 us; speedup vs baseline: 1.8132x; 1.2295x over previous
//
#include <hip/hip_runtime.h>

#define NROWS 4096
#define DCOLS 8192
#define DIM   256
#define NHALF 4096

typedef __attribute__((ext_vector_type(8))) short bf16x8;
typedef __attribute__((ext_vector_type(4))) float f32x4;
typedef __attribute__((ext_vector_type(4))) unsigned short ushort4v;
typedef __attribute__((ext_vector_type(8))) unsigned short ushort8v;
typedef __attribute__((ext_vector_type(4))) _Float16 half4;
typedef __attribute__((ext_vector_type(8))) _Float16 half8;

static __device__ __forceinline__ unsigned short f2bf(float f) {
  union { float f; unsigned int i; } v; v.f = f;
  unsigned int x = v.i;
  return (unsigned short)((x + 0x7fffu + ((x >> 16) & 1u)) >> 16);
}

static __device__ __forceinline__ void gload_lds16(const void* g, void* l) {
  __builtin_amdgcn_global_load_lds(
      (const __attribute__((address_space(1))) void*)g,
      (__attribute__((address_space(3))) void*)l, 16, 0, 0);
}

#define WREDUCE(v) { v += __shfl_xor(v, 1); v += __shfl_xor(v, 2); v += __shfl_xor(v, 4); \
                     v += __shfl_xor(v, 8); v += __shfl_xor(v, 16); v += __shfl_xor(v, 32); }

// ---------------- prep: bf16 convert + row norms (wave per row, float4) ----------------
__global__ __launch_bounds__(256) void k_prep(
    const float* __restrict__ x, const float* __restrict__ ypos,
    const float* __restrict__ yneg, unsigned short* __restrict__ xb,
    unsigned short* __restrict__ yb, float* __restrict__ xx, float* __restrict__ yy) {
  const int lane = threadIdx.x & 63, w = threadIdx.x >> 6;
  const int b = blockIdx.x * 4 + w;   // 0..12287
  const float* src; unsigned short* dst; float* nrm;
  if (b < 4096)      { src = x + (size_t)b * DIM;             dst = xb + (size_t)b * DIM;            nrm = xx + b; }
  else if (b < 8192) { int r = b - 4096; src = yneg + (size_t)r * DIM; dst = yb + (size_t)r * DIM;   nrm = yy + r; }
  else               { int r = b - 8192; src = ypos + (size_t)r * DIM; dst = yb + (size_t)(NHALF + r) * DIM; nrm = yy + NHALF + r; }
  float4 v = *(const float4*)(src + lane * 4);
  ushort4v ov = { f2bf(v.x), f2bf(v.y), f2bf(v.z), f2bf(v.w) };
  *(ushort4v*)(dst + lane * 4) = ov;
  float s = v.x * v.x + v.y * v.y + v.z * v.z + v.w * v.w;
  WREDUCE(s);
  if (lane == 0) nrm[0] = s;
}

// ---------------- transpose yb (8192x256) -> ybt (256x8192) ----------------
__global__ __launch_bounds__(256) void k_transpose(
    const unsigned short* __restrict__ yb, unsigned short* __restrict__ ybt) {
  __shared__ unsigned short tile[64][68];
  int r0 = blockIdx.x * 64;
  int c0 = blockIdx.y * 64;
  int tx = threadIdx.x & 63, ty = threadIdx.x >> 6;
  #pragma unroll
  for (int it = 0; it < 16; ++it) {
    int r = it * 4 + ty;
    tile[r][tx] = yb[(size_t)(r0 + r) * DIM + c0 + tx];
  }
  __syncthreads();
  #pragma unroll
  for (int it = 0; it < 16; ++it) {
    int c = it * 4 + ty;
    ybt[(size_t)(c0 + c) * DCOLS + r0 + tx] = tile[tx][c];
  }
}

// ---------------- dist GEMM: dist[i][j] fp16, + mean(dist_pos) ----------------
__global__ __launch_bounds__(256) void k_dist(
    const unsigned short* __restrict__ xb, const unsigned short* __restrict__ yb,
    const float* __restrict__ xx, const float* __restrict__ yy,
    unsigned short* __restrict__ distbuf, double* __restrict__ meanacc) {
  __shared__ unsigned short As[128 * 64];
  __shared__ unsigned short Bs[128 * 64];
  __shared__ float red[4];
  const int bj = blockIdx.x * 128;
  const int bi = blockIdx.y * 128;
  const int tid = threadIdx.x;
  const int lane = tid & 63, wid = tid >> 6;
  const int wr = wid >> 1, wc = wid & 1;
  f32x4 acc[4][4];
  #pragma unroll
  for (int m = 0; m < 4; ++m)
    #pragma unroll
    for (int n = 0; n < 4; ++n) acc[m][n] = (f32x4){0.f, 0.f, 0.f, 0.f};

  for (int k0 = 0; k0 < DIM; k0 += 64) {
    __syncthreads();
    #pragma unroll
    for (int it = 0; it < 4; ++it) {
      int L = it * 256 + tid;
      int row = L >> 3;
      int cb = (L & 7) * 16;
      int cbs = cb ^ ((row & 7) << 4);
      gload_lds16(xb + (size_t)(bi + row) * DIM + k0 + (cbs >> 1), (char*)As + L * 16);
      gload_lds16(yb + (size_t)(bj + row) * DIM + k0 + (cbs >> 1), (char*)Bs + L * 16);
    }
    __syncthreads();
    #pragma unroll
    for (int kk = 0; kk < 2; ++kk) {
      bf16x8 a[4], b[4];
      #pragma unroll
      for (int m = 0; m < 4; ++m) {
        int row = wr * 64 + m * 16 + (lane & 15);
        int cb = (kk * 64 + ((lane >> 4) * 16)) ^ ((row & 7) << 4);
        a[m] = *(const bf16x8*)((const char*)As + row * 128 + cb);
      }
      #pragma unroll
      for (int n = 0; n < 4; ++n) {
        int row = wc * 64 + n * 16 + (lane & 15);
        int cb = (kk * 64 + ((lane >> 4) * 16)) ^ ((row & 7) << 4);
        b[n] = *(const bf16x8*)((const char*)Bs + row * 128 + cb);
      }
      #pragma unroll
      for (int m = 0; m < 4; ++m)
        #pragma unroll
        for (int n = 0; n < 4; ++n)
          acc[m][n] = __builtin_amdgcn_mfma_f32_16x16x32_bf16(a[m], b[n], acc[m][n], 0, 0, 0);
    }
  }

  const bool pos = (bj >= NHALF);
  float xv[16], yv[4];
  #pragma unroll
  for (int m = 0; m < 4; ++m)
    #pragma unroll
    for (int r = 0; r < 4; ++r)
      xv[m * 4 + r] = xx[bi + wr * 64 + m * 16 + (lane >> 4) * 4 + r];
  #pragma unroll
  for (int n = 0; n < 4; ++n)
    yv[n] = yy[bj + wc * 64 + n * 16 + (lane & 15)];

  _Float16* dp = (_Float16*)distbuf;
  float lsum = 0.f;
  #pragma unroll
  for (int m = 0; m < 4; ++m) {
    #pragma unroll
    for (int n = 0; n < 4; ++n) {
      #pragma unroll
      for (int r = 0; r < 4; ++r) {
        int gi = bi + wr * 64 + m * 16 + (lane >> 4) * 4 + r;
        int gj = bj + wc * 64 + n * 16 + (lane & 15);
        float d2 = xv[m * 4 + r] + yv[n] - 2.f * acc[m][n][r];
        float d = sqrtf(fmaxf(d2, 0.f));
        dp[(size_t)gi * DCOLS + gj] = (_Float16)d;
        lsum += d;
      }
    }
  }
  if (pos) {
    WREDUCE(lsum);
    if (lane == 0) red[wid] = lsum;
    __syncthreads();
    if (tid == 0) atomicAdd(meanacc, (double)(red[0] + red[1] + red[2] + red[3]));
  }
}

// ---------------- exp pass: d -> e2 fp16 in place; col partials + row partials ----------------
// e2 = exp(-d*ia2); e1 = e2^2; e0 = e2^4  (ia0 = 4*ia2, ia1 = 2*ia2)
__global__ __launch_bounds__(256) void k_expcs(
    unsigned short* __restrict__ buf, const double* __restrict__ meanacc,
    float* __restrict__ cs_part, float* __restrict__ rs_part) {
  const int cb = blockIdx.x & 7, rb = blockIdx.x >> 3;  // rb 0..127
  const int t = threadIdx.x;
  const int lane = t & 63, w = t >> 6;
  const int c0 = cb * 1024 + t * 4;
  const int slab = cb * 4 + w;                          // 0..31
  const float md = (float)(meanacc[0] * (1.0 / 16777216.0));
  const float ia2 = 1.f / (0.2f * md);
  float a0[4] = {0,0,0,0}, a1[4] = {0,0,0,0}, a2[4] = {0,0,0,0};
  const int rbeg = rb * 32;
  for (int r = rbeg; r < rbeg + 32; ++r) {
    size_t base = (size_t)r * DCOLS + c0;
    half4 h = *(const half4*)((const _Float16*)buf + base);
    float rs2 = 0.f, rs1 = 0.f, rs0 = 0.f;
    half4 eh;
    #pragma unroll
    for (int u = 0; u < 4; ++u) {
      float d = (float)h[u];
      float q = __expf(-d * ia2);
      if (c0 + u == r) q = 0.f;        // diagonal mask (only occurs in neg half)
      float q2 = q * q, q4 = q2 * q2;
      a2[u] += q; a1[u] += q2; a0[u] += q4;
      rs2 += q; rs1 += q2; rs0 += q4;
      eh[u] = (_Float16)q;
    }
    *(half4*)((_Float16*)buf + base) = eh;
    WREDUCE(rs0); WREDUCE(rs1); WREDUCE(rs2);
    if (lane == 0) {
      rs_part[(size_t)slab * 12288 + 0 * 4096 + r] = rs0;
      rs_part[(size_t)slab * 12288 + 1 * 4096 + r] = rs1;
      rs_part[(size_t)slab * 12288 + 2 * 4096 + r] = rs2;
    }
  }
  *(f32x4*)(cs_part + (size_t)rb * 24576 + 0 * 8192 + c0) = (f32x4){a0[0], a0[1], a0[2], a0[3]};
  *(f32x4*)(cs_part + (size_t)rb * 24576 + 1 * 8192 + c0) = (f32x4){a1[0], a1[1], a1[2], a1[3]};
  *(f32x4*)(cs_part + (size_t)rb * 24576 + 2 * 8192 + c0) = (f32x4){a2[0], a2[1], a2[2], a2[3]};
}

// ---------------- reduce partials: ich = fp16 rsqrt(colsum); rsums = row sums ----------------
__global__ __launch_bounds__(256) void k_csred(
    const float* __restrict__ cs_part, const float* __restrict__ rs_part,
    _Float16* __restrict__ ich, float* __restrict__ rsums) {
  int idx = blockIdx.x * 256 + threadIdx.x;   // grid 144 -> 36864
  if (idx < 24576) {
    float s = 0.f;
    #pragma unroll 8
    for (int rb = 0; rb < 128; ++rb) s += cs_part[(size_t)rb * 24576 + idx];
    ich[idx] = (_Float16)rsqrtf(s);
  } else {
    int ridx = idx - 24576;                    // [0,12288): [3][4096]
    float s = 0.f;
    #pragma unroll 8
    for (int sl = 0; sl < 32; ++sl) s += rs_part[(size_t)sl * 12288 + ridx];
    rsums[ridx] = s;
  }
}

// ---------------- fused Sn/Sp + C write (block per row, no transcendentals) ----------------
__global__ __launch_bounds__(256) void k_rows(
    unsigned short* __restrict__ buf, const _Float16* __restrict__ ich,
    const float* __restrict__ rsums) {
  __shared__ float red[4][3];
  const int lane = threadIdx.x & 63, w = threadIdx.x >> 6;
  const int i = blockIdx.x;                 // row
  unsigned short* rowp = buf + (size_t)i * DCOLS;
  const _Float16* erow = (const _Float16*)rowp;

  // pass B: per-wave weighted sums  S_t = sum e_t * ic_t  over this wave's 2048 cols
  float s0 = 0.f, s1 = 0.f, s2 = 0.f;
  #pragma unroll 2
  for (int it = 0; it < 4; ++it) {
    int j0 = w * 2048 + it * 512 + lane * 8;
    half8 e8 = *(const half8*)(erow + j0);
    half8 c0v = *(const half8*)(ich + j0);
    half8 c1v = *(const half8*)(ich + 8192 + j0);
    half8 c2v = *(const half8*)(ich + 16384 + j0);
    #pragma unroll
    for (int u = 0; u < 8; ++u) {
      float q = (float)e8[u];
      float q2 = q * q, q4 = q2 * q2;
      s0 += q4 * (float)c0v[u];
      s1 += q2 * (float)c1v[u];
      s2 += q  * (float)c2v[u];
    }
  }
  WREDUCE(s0); WREDUCE(s1); WREDUCE(s2);
  if (lane == 0) { red[w][0] = s0; red[w][1] = s1; red[w][2] = s2; }
  __syncthreads();

  // g_t per wave-half:  neg cols: -Sp_t/r_t ;  pos cols: +Sn_t/r_t
  float g0, g1, g2;
  {
    float Sn0 = red[0][0] + red[1][0], Sp0 = red[2][0] + red[3][0];
    float Sn1 = red[0][1] + red[1][1], Sp1 = red[2][1] + red[3][1];
    float Sn2 = red[0][2] + red[1][2], Sp2 = red[2][2] + red[3][2];
    float r0 = rsums[i], r1 = rsums[4096 + i], r2 = rsums[8192 + i];
    if (w < 2) { g0 = -Sp0 / r0; g1 = -Sp1 / r1; g2 = -Sp2 / r2; }
    else       { g0 =  Sn0 / r0; g1 =  Sn1 / r1; g2 =  Sn2 / r2; }
  }

  // pass C: C_ij = e0*ic0*g0 + e1*ic1*g1 + e2*ic2*g2   (bf16, in place)
  #pragma unroll 2
  for (int it = 0; it < 4; ++it) {
    int j0 = w * 2048 + it * 512 + lane * 8;
    half8 e8 = *(const half8*)(erow + j0);
    half8 c0v = *(const half8*)(ich + j0);
    half8 c1v = *(const half8*)(ich + 8192 + j0);
    half8 c2v = *(const half8*)(ich + 16384 + j0);
    ushort8v outv;
    #pragma unroll
    for (int u = 0; u < 8; ++u) {
      float q = (float)e8[u];
      float q2 = q * q, q4 = q2 * q2;
      float C = q4 * (float)c0v[u] * g0 + q2 * (float)c1v[u] * g1 + q * (float)c2v[u] * g2;
      outv[u] = f2bf(C);
    }
    *(ushort8v*)(rowp + j0) = outv;
  }
}

// ---------------- V GEMM: vpart[kc] = C[:, kc-chunk] @ Yb[kc-chunk, :] ----------------
__global__ __launch_bounds__(256) void k_vgemm(
    const unsigned short* __restrict__ cm, const unsigned short* __restrict__ ybt,
    float* __restrict__ vpart) {
  __shared__ unsigned short As[128 * 64];
  __shared__ unsigned short Bs[128 * 64];
  const int kc = blockIdx.x;   // 0..3
  const int cb = blockIdx.y;   // 0..1
  const int rb = blockIdx.z;   // 0..31
  const int tid = threadIdx.x;
  const int lane = tid & 63, wid = tid >> 6;
  const int wr = wid >> 1, wc = wid & 1;
  f32x4 acc[4][4];
  #pragma unroll
  for (int m = 0; m < 4; ++m)
    #pragma unroll
    for (int n = 0; n < 4; ++n) acc[m][n] = (f32x4){0.f, 0.f, 0.f, 0.f};

  for (int jt = 0; jt < 2048; jt += 64) {
    const int j0 = kc * 2048 + jt;
    __syncthreads();
    #pragma unroll
    for (int it = 0; it < 4; ++it) {
      int L = it * 256 + tid;
      int row = L >> 3;
      int cbyte = (L & 7) * 16;
      int cbs = cbyte ^ ((row & 7) << 4);
      gload_lds16(cm + (size_t)(rb * 128 + row) * DCOLS + j0 + (cbs >> 1), (char*)As + L * 16);
      gload_lds16(ybt + (size_t)(cb * 128 + row) * DCOLS + j0 + (cbs >> 1), (char*)Bs + L * 16);
    }
    __syncthreads();
    #pragma unroll
    for (int kk = 0; kk < 2; ++kk) {
      bf16x8 a[4], b[4];
      #pragma unroll
      for (int m = 0; m < 4; ++m) {
        int row = wr * 64 + m * 16 + (lane & 15);
        int cbyte = (kk * 64 + ((lane >> 4) * 16)) ^ ((row & 7) << 4);
        a[m] = *(const bf16x8*)((const char*)As + row * 128 + cbyte);
      }
      #pragma unroll
      for (int n = 0; n < 4; ++n) {
        int row = wc * 64 + n * 16 + (lane & 15);
        int cbyte = (kk * 64 + ((lane >> 4) * 16)) ^ ((row & 7) << 4);
        b[n] = *(const bf16x8*)((const char*)Bs + row * 128 + cbyte);
      }
      #pragma unroll
      for (int m = 0; m < 4; ++m)
        #pragma unroll
        for (int n = 0; n < 4; ++n)
          acc[m][n] = __builtin_amdgcn_mfma_f32_16x16x32_bf16(a[m], b[n], acc[m][n], 0, 0, 0);
    }
  }
  #pragma unroll
  for (int m = 0; m < 4; ++m)
    #pragma unroll
    for (int n = 0; n < 4; ++n)
      #pragma unroll
      for (int r = 0; r < 4; ++r) {
        int gi = rb * 128 + wr * 64 + m * 16 + (lane >> 4) * 4 + r;
        int gd = cb * 128 + wc * 64 + n * 16 + (lane & 15);
        vpart[(size_t)kc * 1048576 + (size_t)gi * 256 + gd] = acc[m][n][r];
      }
}

// ---------------- loss reduction ----------------
__global__ __launch_bounds__(256) void k_loss(
    const float* __restrict__ vpart, float* __restrict__ ploss) {
  int tid = blockIdx.x * 256 + threadIdx.x;   // grid 512
  float s = 0.f;
  for (int e = tid; e < 1048576; e += 131072) {
    float v = vpart[e] + vpart[e + 1048576] + vpart[e + 2097152] + vpart[e + 3145728];
    s += v * v;
  }
  WREDUCE(s);
  __shared__ float red[4];
  if ((threadIdx.x & 63) == 0) red[threadIdx.x >> 6] = s;
  __syncthreads();
  if (threadIdx.x == 0) ploss[blockIdx.x] = red[0] + red[1] + red[2] + red[3];
}

__global__ __launch_bounds__(256) void k_finish(
    const float* __restrict__ ploss, float* __restrict__ out) {
  float v = ploss[threadIdx.x] + ploss[threadIdx.x + 256];
  WREDUCE(v);
  __shared__ float red[4];
  if ((threadIdx.x & 63) == 0) red[threadIdx.x >> 6] = v;
  __syncthreads();
  if (threadIdx.x == 0)
    out[0] = (float)((double)(red[0] + red[1] + red[2] + red[3]) / 1048576.0);
}

extern "C" void kernel_launch(void* const* d_in, const int* in_sizes, int n_in,
                              void* d_out, int out_size, void* d_ws, size_t ws_size,
                              hipStream_t stream) {
  (void)in_sizes; (void)n_in; (void)out_size; (void)ws_size;
  const float* x    = (const float*)d_in[0];
  const float* ypos = (const float*)d_in[1];
  const float* yneg = (const float*)d_in[2];

  char* ws = (char*)d_ws;
  size_t o = 0;
  unsigned short* dist = (unsigned short*)(ws + o); o += (size_t)NROWS * DCOLS * 2;  // 64 MiB (d -> e2 -> C)
  unsigned short* xb   = (unsigned short*)(ws + o); o += (size_t)NROWS * DIM * 2;    // 2 MiB
  unsigned short* yb   = (unsigned short*)(ws + o); o += (size_t)DCOLS * DIM * 2;    // 4 MiB
  unsigned short* ybt  = (unsigned short*)(ws + o); o += (size_t)DCOLS * DIM * 2;    // 4 MiB
  float* xx      = (float*)(ws + o); o += NROWS * 4;
  float* yy      = (float*)(ws + o); o += DCOLS * 4;
  double* meanacc = (double*)(ws + o); o += 256;
  _Float16* ich  = (_Float16*)(ws + o); o += 3 * DCOLS * 2;      // 48 KiB fp16 rsqrt(colsum)
  float* rsums   = (float*)(ws + o); o += 3 * NROWS * 4;         // 48 KiB
  float* ploss   = (float*)(ws + o); o += 512 * 4;
  // union region: {cs_part 12 MiB + rs_part 1.5 MiB} aliased with vpart (16 MiB)
  float* cs_part = (float*)(ws + o);
  float* rs_part = (float*)(ws + o + (size_t)128 * 24576 * 4);
  float* vpart   = (float*)(ws + o); o += (size_t)4 * NROWS * DIM * 4;               // 16 MiB

  hipMemsetAsync(meanacc, 0, 8, stream);
  k_prep<<<3072, 256, 0, stream>>>(x, ypos, yneg, xb, yb, xx, yy);
  k_transpose<<<dim3(128, 4), 256, 0, stream>>>(yb, ybt);
  k_dist<<<dim3(64, 32), 256, 0, stream>>>(xb, yb, xx, yy, dist, meanacc);
  k_expcs<<<1024, 256, 0, stream>>>(dist, meanacc, cs_part, rs_part);
  k_csred<<<144, 256, 0, stream>>>(cs_part, rs_part, ich, rsums);
  k_rows<<<4096, 256, 0, stream>>>(dist, ich, rsums);
  k_vgemm<<<dim3(4, 2, 32), 256, 0, stream>>>(dist, ybt, vpart);
  k_loss<<<512, 256, 0, stream>>>(vpart, ploss);
  k_finish<<<1, 256, 0, stream>>>(ploss, (float*)d_out);
}